// Round 12
// baseline (311.425 us; speedup 1.0000x reference)
//
#include <hip/hip_runtime.h>
#include <hip/hip_bf16.h>

#define B_    128
#define T_    2048
#define OBS_  128
#define S_    128
#define OUT_  64
#define H_    64
#define NR    (B_*T_)            // 262144 rows
#define K_CH  16                 // chunk length
#define C_CH  128                // number of chunks
#define VOFF  (NR*2*OUT_)        // 33554432 : cur_value offset in d_out
#define XFOFF (VOFF + NR)        // 33816576 : x_final offset in d_out

typedef __attribute__((ext_vector_type(8))) short short8v;   // 8 bf16 (4 VGPRs)
typedef __attribute__((ext_vector_type(4))) float f32x4;

__device__ __forceinline__ unsigned short f2bf_hw(float f){
  __hip_bfloat16 h = __float2bfloat16(f);
  union { __hip_bfloat16 hh; unsigned short u; } cv; cv.hh = h; return cv.u;
}
__device__ __forceinline__ unsigned int pk2(float a, float b){
  __hip_bfloat162 h = __float22bfloat162_rn(make_float2(a, b));
  union { __hip_bfloat162 h2; unsigned int u; } cv; cv.h2 = h; return cv.u;
}
__device__ __forceinline__ float bf2f(unsigned short h){
  return __uint_as_float(((unsigned int)h) << 16);
}
__device__ __forceinline__ float fast_tanh(float x){
  float z = __builtin_exp2f(x * 2.88539008f);
  return 1.f - 2.f * __builtin_amdgcn_rcpf(z + 1.f);
}

// ---------------- generic 128x128 @ 128x128 matmul
__global__ __launch_bounds__(256) void k_mm(const float* __restrict__ A,
                                            const float* __restrict__ B,
                                            float* __restrict__ C, int ldc){
  int e = blockIdx.x * 256 + threadIdx.x;
  int r = e >> 7, c = e & 127;
  float acc = 0.f;
  #pragma unroll 4
  for (int k = 0; k < 128; ++k) acc += A[r*128 + k] * B[k*128 + c];
  C[r*ldc + c] = acc;
}

// ---------------- A3 = A2*A ; A4 = A2*A2
__global__ __launch_bounds__(256) void k_mm2(const float* __restrict__ A_T,
                                             const float* __restrict__ A2,
                                             float* __restrict__ A3,
                                             float* __restrict__ A4){
  int e = blockIdx.x * 256 + threadIdx.x;
  int r = e >> 7, c = e & 127;
  float a3 = 0.f, a4 = 0.f;
  #pragma unroll 4
  for (int k = 0; k < 128; ++k){
    float l = A2[r*128 + k];
    a3 += l * A_T[k*128 + c];
    a4 += l * A2[k*128 + c];
  }
  A3[e] = a3; A4[e] = a4;
}

// ---------------- build M, Mmi(bf16), P, Duy->Wcat, Cu->bf16
__global__ __launch_bounds__(256) void k_build(const float* __restrict__ A_T,
                                               const float* __restrict__ A2,
                                               const float* __restrict__ A3,
                                               const float* __restrict__ A4,
                                               const float* __restrict__ Cu_T,
                                               const float* __restrict__ Duy_T,
                                               const float* __restrict__ dtp,
                                               float* __restrict__ M,
                                               unsigned short* __restrict__ Mmibf,
                                               float* __restrict__ P, float* __restrict__ Wcat,
                                               unsigned short* __restrict__ cubf){
  float dt = *dtp;
  float d2 = dt*dt*0.5f;
  float d3 = d2*dt*(1.f/3.f);
  float d4 = d3*dt*0.25f;
  int e = blockIdx.x * 256 + threadIdx.x;
  int r = e >> 7, c = e & 127;
  float eye = (r == c) ? 1.f : 0.f;
  float mi = dt*A_T[e] + d2*A2[e] + d3*A3[e] + d4*A4[e];
  M[e] = eye + mi;
  Mmibf[e] = f2bf_hw(mi);
  P[e] = dt*eye + d2*A_T[e] + d3*A2[e] + d4*A3[e];
  if (e < 128*64){
    int k = e >> 6, o = e & 63;
    Wcat[k*192 + 128 + o] = Duy_T[e];
    cubf[e] = f2bf_hw(Cu_T[e]);
  }
}

// ---------------- Wcat-G = By*P ; sq1 = M^2
__global__ __launch_bounds__(256) void k_gm2(const float* __restrict__ By_T,
                                             const float* __restrict__ Pp,
                                             const float* __restrict__ Mm,
                                             float* __restrict__ Wcat,
                                             float* __restrict__ sq1){
  int e = blockIdx.x * 256 + threadIdx.x;
  int r = e >> 7, c = e & 127;
  float ga = 0.f, m2 = 0.f;
  #pragma unroll 4
  for (int k = 0; k < 128; ++k){
    ga += By_T[r*128 + k] * Pp[k*128 + c];
    m2 += Mm[r*128 + k] * Mm[k*128 + c];
  }
  Wcat[r*192 + c] = ga;
  sq1[e] = m2;
}

// ---------------- sq2 = M^4 ; convert Wbf/W0bf/W1bf
__global__ __launch_bounds__(256) void k_m4cvt(const float* __restrict__ sq1,
                                               const float* __restrict__ Wcat,
                                               const float* __restrict__ W0,
                                               const float* __restrict__ W1,
                                               float* __restrict__ sq2,
                                               unsigned short* __restrict__ Wbf,
                                               unsigned short* __restrict__ W0bf,
                                               unsigned short* __restrict__ W1bf){
  int e = blockIdx.x * 256 + threadIdx.x;
  int r = e >> 7, c = e & 127;
  float m4 = 0.f;
  #pragma unroll 4
  for (int k = 0; k < 128; ++k) m4 += sq1[r*128 + k] * sq1[k*128 + c];
  sq2[e] = m4;
  for (int i = e; i < 24576; i += 16384) Wbf[i] = f2bf_hw(Wcat[i]);
  if (e < 8192) W0bf[e] = f2bf_hw(W0[e]);
  if (e < 4096) W1bf[e] = f2bf_hw(W1[e]);
}

// ---------------- fused B1+B2 (MFMA), 128-row blocks, LDS-staged + prefetch
__global__ __launch_bounds__(256) void k_fused(const float* __restrict__ obs,
                                               const unsigned short* __restrict__ Wbf,
                                               const unsigned short* __restrict__ W0bf,
                                               const unsigned short* __restrict__ W1bf,
                                               const float* __restrict__ W2,
                                               const float* __restrict__ b0g,
                                               const float* __restrict__ b1g,
                                               const float* __restrict__ b2g,
                                               const float* __restrict__ ls,
                                               unsigned short* __restrict__ cuy,
                                               float* __restrict__ out){
  __shared__ __align__(16) unsigned short ylds[64*136];  // 17408 B
  __shared__ __align__(16) unsigned short ct[2][16*200]; // 12800 B (double buffer)
  __shared__ __align__(16) unsigned short h0l[128*80];   // 20480 B
  __shared__ float pl[128][4];                           //  2048 B
  int tid = threadIdx.x;
  int lane = tid & 63, w = tid >> 6;
  size_t row0 = (size_t)blockIdx.x * 128;
  int colbase = w * 48;
  int colh    = w * 16;
  int lr = lane & 15;
  int lk = (lane >> 4) * 8;

  short8v bfrag[3][4];
  #pragma unroll
  for (int cf = 0; cf < 3; ++cf)
    #pragma unroll
    for (int kk = 0; kk < 4; ++kk){
      short8v b;
      #pragma unroll
      for (int j = 0; j < 8; ++j)
        b[j] = (short)Wbf[(size_t)(kk*32 + lk + j)*192 + (colbase + cf*16 + lr)];
      bfrag[cf][kk] = b;
    }
  short8v bw0[4];
  #pragma unroll
  for (int kk = 0; kk < 4; ++kk)
    bw0[kk] = *(const short8v*)&W0bf[(size_t)(colh + lr)*128 + kk*32 + lk];
  short8v bw1[2];
  #pragma unroll
  for (int kk = 0; kk < 2; ++kk)
    bw1[kk] = *(const short8v*)&W1bf[(size_t)(colh + lr)*64 + kk*32 + lk];
  float b0v = b0g[colh + lr];
  float b1v = b1g[colh + lr];
  float w2v = W2[colh + lr];

  int sbase = tid * 32;
  int sr = sbase >> 7, sc0 = sbase & 127;
  float4 pa[4], pb[4];
  { // prefetch h=0
    const float* grow = obs + (row0 + sr) * 128;
    #pragma unroll
    for (int it = 0; it < 4; ++it){
      pa[it] = *(const float4*)&grow[sc0 + it*8];
      pb[it] = *(const float4*)&grow[sc0 + it*8 + 4];
    }
  }
  for (int h = 0; h < 2; ++h){
    #pragma unroll
    for (int it = 0; it < 4; ++it){
      uint4 pv;
      pv.x = pk2(pa[it].x, pa[it].y); pv.y = pk2(pa[it].z, pa[it].w);
      pv.z = pk2(pb[it].x, pb[it].y); pv.w = pk2(pb[it].z, pb[it].w);
      *(uint4*)&ylds[sr*136 + sc0 + it*8] = pv;
    }
    __syncthreads();
    if (h == 0){ // prefetch h=1 during h=0 compute
      const float* grow = obs + (row0 + 64 + sr) * 128;
      #pragma unroll
      for (int it = 0; it < 4; ++it){
        pa[it] = *(const float4*)&grow[sc0 + it*8];
        pb[it] = *(const float4*)&grow[sc0 + it*8 + 4];
      }
    }
    for (int rfh = 0; rfh < 4; ++rfh){
      int rf = h*4 + rfh;
      f32x4 acc0 = {0.f,0.f,0.f,0.f}, acc1 = {0.f,0.f,0.f,0.f}, acc2 = {0.f,0.f,0.f,0.f};
      f32x4 acch = {0.f,0.f,0.f,0.f};
      #pragma unroll
      for (int kk = 0; kk < 4; ++kk){
        short8v af = *(const short8v*)&ylds[(rfh*16 + lr)*136 + kk*32 + lk];
        acc0 = __builtin_amdgcn_mfma_f32_16x16x32_bf16(af, bfrag[0][kk], acc0, 0, 0, 0);
        acc1 = __builtin_amdgcn_mfma_f32_16x16x32_bf16(af, bfrag[1][kk], acc1, 0, 0, 0);
        acc2 = __builtin_amdgcn_mfma_f32_16x16x32_bf16(af, bfrag[2][kk], acc2, 0, 0, 0);
        acch = __builtin_amdgcn_mfma_f32_16x16x32_bf16(af, bw0[kk],     acch, 0, 0, 0);
      }
      int orow = rf*16 + (lane >> 4)*4;
      int crow = (lane >> 4)*4;
      unsigned short* ctb = ct[rfh & 1];
      #pragma unroll
      for (int j = 0; j < 4; ++j){
        ctb[(crow + j)*200 + colbase      + lr] = f2bf_hw(acc0[j]);
        ctb[(crow + j)*200 + colbase + 16 + lr] = f2bf_hw(acc1[j]);
        ctb[(crow + j)*200 + colbase + 32 + lr] = f2bf_hw(acc2[j]);
        h0l[(orow + j)*80 + colh + lr]          = f2bf_hw(fast_tanh(acch[j] + b0v));
      }
      __syncthreads();
      for (int li = tid; li < 16*24; li += 256){
        int r = li / 24, seg = li % 24;
        *(uint4*)&cuy[(row0 + h*64 + rfh*16 + r)*192 + seg*8] = *(const uint4*)&ctb[r*200 + seg*8];
      }
    }
    __syncthreads();
  }

  for (int rf = 0; rf < 8; ++rf){
    f32x4 acc = {b1v, b1v, b1v, b1v};
    #pragma unroll
    for (int kk = 0; kk < 2; ++kk){
      short8v af = *(const short8v*)&h0l[(rf*16 + lr)*80 + kk*32 + lk];
      acc = __builtin_amdgcn_mfma_f32_16x16x32_bf16(af, bw1[kk], acc, 0, 0, 0);
    }
    float4 vpart;
    #pragma unroll
    for (int j = 0; j < 4; ++j) (&vpart.x)[j] = fast_tanh(acc[j]) * w2v;
    #pragma unroll
    for (int m = 1; m < 16; m <<= 1){
      vpart.x += __shfl_xor(vpart.x, m);
      vpart.y += __shfl_xor(vpart.y, m);
      vpart.z += __shfl_xor(vpart.z, m);
      vpart.w += __shfl_xor(vpart.w, m);
    }
    if (lr == 0){
      int orow = rf*16 + (lane >> 4)*4;
      #pragma unroll
      for (int j = 0; j < 4; ++j) pl[orow + j][w] = (&vpart.x)[j];
    }
  }
  __syncthreads();

  if (tid < 128)
    out[(size_t)VOFF + row0 + tid] = pl[tid][0] + pl[tid][1] + pl[tid][2] + pl[tid][3] + b2g[0];
  for (int li = tid; li < 128*16; li += 256){
    int r = li >> 4, c4 = li & 15;
    float4 lv = *(const float4*)&ls[c4*4];
    *(float4*)&out[(row0 + r)*128 + 64 + c4*4] = lv;
  }
}

// ---------------- phase 1 (MFMA), 16-row blocks: zero-init scan -> deltas
__global__ __launch_bounds__(256) void k_phase1(const unsigned short* __restrict__ cuy,
                                                const unsigned short* __restrict__ Mmibf,
                                                float* __restrict__ Dd){
  __shared__ __align__(16) unsigned short xw[16*136];
  int tid = threadIdx.x;
  int lane = tid & 63, w = tid >> 6;
  int lr = lane & 15, lg = lane >> 4;
  int ci = blockIdx.x >> 3, bi = blockIdx.x & 7;
  int b0 = bi*16, t0 = ci*K_CH;
  int colbase = w*32;

  short8v bm[2][4];
  #pragma unroll
  for (int ctt = 0; ctt < 2; ++ctt)
    #pragma unroll
    for (int kk = 0; kk < 4; ++kk){
      short8v b;
      #pragma unroll
      for (int j = 0; j < 8; ++j)
        b[j] = (short)Mmibf[(size_t)(kk*32 + lg*8 + j)*128 + colbase + ctt*16 + lr];
      bm[ctt][kk] = b;
    }

  f32x4 acc[2];
  #pragma unroll
  for (int ctt = 0; ctt < 2; ++ctt)
    #pragma unroll
    for (int j = 0; j < 4; ++j)
      acc[ctt][j] = bf2f(cuy[((size_t)(b0 + lg*4 + j)*T_ + t0)*192 + colbase + ctt*16 + lr]);

  for (int s = 1; s < K_CH; ++s){
    unsigned short cn[2][4];
    #pragma unroll
    for (int ctt = 0; ctt < 2; ++ctt)
      #pragma unroll
      for (int j = 0; j < 4; ++j)
        cn[ctt][j] = cuy[((size_t)(b0 + lg*4 + j)*T_ + t0 + s)*192 + colbase + ctt*16 + lr];
    #pragma unroll
    for (int ctt = 0; ctt < 2; ++ctt)
      #pragma unroll
      for (int j = 0; j < 4; ++j)
        xw[(lg*4 + j)*136 + colbase + ctt*16 + lr] = f2bf_hw(acc[ctt][j]);
    __syncthreads();
    short8v af[4];
    #pragma unroll
    for (int kk = 0; kk < 4; ++kk)
      af[kk] = *(const short8v*)&xw[lr*136 + kk*32 + lg*8];
    __syncthreads();
    #pragma unroll
    for (int ctt = 0; ctt < 2; ++ctt)
      #pragma unroll
      for (int kk = 0; kk < 4; ++kk)
        acc[ctt] = __builtin_amdgcn_mfma_f32_16x16x32_bf16(af[kk], bm[ctt][kk], acc[ctt], 0, 0, 0);
    #pragma unroll
    for (int ctt = 0; ctt < 2; ++ctt)
      #pragma unroll
      for (int j = 0; j < 4; ++j)
        acc[ctt][j] += bf2f(cn[ctt][j]);
  }
  #pragma unroll
  for (int ctt = 0; ctt < 2; ++ctt)
    #pragma unroll
    for (int j = 0; j < 4; ++j)
      Dd[(size_t)ci*16384 + (size_t)(b0 + lg*4 + j)*128 + colbase + ctt*16 + lr] = acc[ctt][j];
}

// ---------------- combine: sequential over 128 chunks, parallel over batch rows
__global__ __launch_bounds__(256) void k_combine(const float* __restrict__ Mk,
                                                 const float* __restrict__ Dd,
                                                 const float* __restrict__ x0,
                                                 float* __restrict__ XS,
                                                 float* __restrict__ xfin){
  __shared__ float xl[128];
  __shared__ float pl[256];
  int tid = threadIdx.x;
  int b = blockIdx.x;
  int c = tid & 127, h = tid >> 7;
  float mreg[64];
  #pragma unroll
  for (int j = 0; j < 64; ++j) mreg[j] = Mk[(64*h + j)*128 + c];
  if (tid < 128) xl[tid] = x0[(size_t)b*128 + tid];
  __syncthreads();
  for (int i = 0; i < C_CH; ++i){
    if (tid < 128) XS[(size_t)i*16384 + (size_t)b*128 + tid] = xl[tid];
    float part = 0.f;
    #pragma unroll
    for (int jj = 0; jj < 64; jj += 4){
      float4 xv = *(const float4*)&xl[64*h + jj];
      part += xv.x*mreg[jj] + xv.y*mreg[jj+1] + xv.z*mreg[jj+2] + xv.w*mreg[jj+3];
    }
    pl[tid] = part;
    __syncthreads();
    if (tid < 128)
      xl[tid] = pl[tid] + pl[tid + 128] + Dd[(size_t)i*16384 + (size_t)b*128 + tid];
    __syncthreads();
  }
  if (tid < 128) xfin[(size_t)b*128 + tid] = xl[tid];
}

// ---------------- phase 3 (MFMA), 16-row blocks: replay + fused u output
__global__ __launch_bounds__(256) void k_phase3(const unsigned short* __restrict__ cuy,
                                                const unsigned short* __restrict__ Mmibf,
                                                const unsigned short* __restrict__ cubf,
                                                const float* __restrict__ XS,
                                                float* __restrict__ out){
  __shared__ __align__(16) unsigned short xw[16*136];
  int tid = threadIdx.x;
  int lane = tid & 63, w = tid >> 6;
  int lr = lane & 15, lg = lane >> 4;
  int ci = blockIdx.x >> 3, bi = blockIdx.x & 7;
  int b0 = bi*16, t0 = ci*K_CH;
  int colbase = w*32;
  int ucolbase = w*16;

  short8v bm[2][4];
  #pragma unroll
  for (int ctt = 0; ctt < 2; ++ctt)
    #pragma unroll
    for (int kk = 0; kk < 4; ++kk){
      short8v b;
      #pragma unroll
      for (int j = 0; j < 8; ++j)
        b[j] = (short)Mmibf[(size_t)(kk*32 + lg*8 + j)*128 + colbase + ctt*16 + lr];
      bm[ctt][kk] = b;
    }
  short8v bc[4];
  #pragma unroll
  for (int kk = 0; kk < 4; ++kk){
    short8v b;
    #pragma unroll
    for (int j = 0; j < 8; ++j)
      b[j] = (short)cubf[(size_t)(kk*32 + lg*8 + j)*64 + ucolbase + lr];
    bc[kk] = b;
  }

  f32x4 acc[2];
  #pragma unroll
  for (int ctt = 0; ctt < 2; ++ctt)
    #pragma unroll
    for (int j = 0; j < 4; ++j)
      acc[ctt][j] = XS[(size_t)ci*16384 + (size_t)(b0 + lg*4 + j)*128 + colbase + ctt*16 + lr];

  for (int s = 0; s < K_CH; ++s){
    f32x4 au;
    #pragma unroll
    for (int j = 0; j < 4; ++j)
      au[j] = bf2f(cuy[((size_t)(b0 + lg*4 + j)*T_ + t0 + s)*192 + 128 + ucolbase + lr]);
    unsigned short cn[2][4];
    if (s + 1 < K_CH){
      #pragma unroll
      for (int ctt = 0; ctt < 2; ++ctt)
        #pragma unroll
        for (int j = 0; j < 4; ++j)
          cn[ctt][j] = cuy[((size_t)(b0 + lg*4 + j)*T_ + t0 + s)*192 + colbase + ctt*16 + lr];
    }
    #pragma unroll
    for (int ctt = 0; ctt < 2; ++ctt)
      #pragma unroll
      for (int j = 0; j < 4; ++j)
        xw[(lg*4 + j)*136 + colbase + ctt*16 + lr] = f2bf_hw(acc[ctt][j]);
    __syncthreads();
    short8v af[4];
    #pragma unroll
    for (int kk = 0; kk < 4; ++kk)
      af[kk] = *(const short8v*)&xw[lr*136 + kk*32 + lg*8];
    __syncthreads();
    #pragma unroll
    for (int kk = 0; kk < 4; ++kk)
      au = __builtin_amdgcn_mfma_f32_16x16x32_bf16(af[kk], bc[kk], au, 0, 0, 0);
    #pragma unroll
    for (int j = 0; j < 4; ++j)
      out[((size_t)(b0 + lg*4 + j)*T_ + t0 + s)*128 + ucolbase + lr] = au[j];
    if (s + 1 < K_CH){
      #pragma unroll
      for (int ctt = 0; ctt < 2; ++ctt)
        #pragma unroll
        for (int kk = 0; kk < 4; ++kk)
          acc[ctt] = __builtin_amdgcn_mfma_f32_16x16x32_bf16(af[kk], bm[ctt][kk], acc[ctt], 0, 0, 0);
      #pragma unroll
      for (int ctt = 0; ctt < 2; ++ctt)
        #pragma unroll
        for (int j = 0; j < 4; ++j)
          acc[ctt][j] += bf2f(cn[ctt][j]);
    }
  }
}

extern "C" void kernel_launch(void* const* d_in, const int* in_sizes, int n_in,
                              void* d_out, int out_size, void* d_ws, size_t ws_size,
                              hipStream_t stream){
  const float* obs  = (const float*)d_in[0];
  const float* x0   = (const float*)d_in[1];
  const float* A_T  = (const float*)d_in[2];
  const float* By_T = (const float*)d_in[3];
  const float* Cu_T = (const float*)d_in[4];
  const float* Duy_T= (const float*)d_in[5];
  const float* ls   = (const float*)d_in[6];
  const float* W0   = (const float*)d_in[7];
  const float* b0   = (const float*)d_in[8];
  const float* W1   = (const float*)d_in[9];
  const float* b1   = (const float*)d_in[10];
  const float* W2   = (const float*)d_in[11];
  const float* b2   = (const float*)d_in[12];
  const float* dt   = (const float*)d_in[13];
  float* out = (float*)d_out;

  char* ws = (char*)d_ws;
  unsigned short* cuy = (unsigned short*)(ws + 0);            // 100663296 B
  float* A2     = (float*)(ws + 100663296);                   // 65536 each
  float* A3     = (float*)(ws + 100728832);
  float* A4     = (float*)(ws + 100794368);
  float* Mm     = (float*)(ws + 100859904);
  float* Pp     = (float*)(ws + 100925440);
  float* Mk     = (float*)(ws + 100990976);
  float* sq1    = (float*)(ws + 101056512);
  float* sq2    = (float*)(ws + 101122048);
  unsigned short* Mmibf = (unsigned short*)(ws + 101187584);  // 32768 B
  float* Wcat   = (float*)(ws + 101255168);                   // 98304 B
  unsigned short* cubf  = (unsigned short*)(ws + 101353472);  // 16384 B
  float* Dd     = (float*)(ws + 101387264);                   // 8388608 B
  float* XS     = (float*)(ws + 109775872);                   // 8388608 B (end 118164480)
  unsigned short* Wbf  = (unsigned short*)Pp;                 // Pp dead after k_gm2 (49152 B)
  unsigned short* W0bf = (unsigned short*)A3;                 // A3 dead after k_build (16384 B)
  unsigned short* W1bf = (unsigned short*)A4;                 // A4 dead after k_build (8192 B)

  // ---- discrete setup chain (7 launches), Mk = M^16
  k_mm   <<<64, 256, 0, stream>>>(A_T, A_T, A2, 128);                    // A^2
  k_mm2  <<<64, 256, 0, stream>>>(A_T, A2, A3, A4);                      // A^3, A^4
  k_build<<<64, 256, 0, stream>>>(A_T, A2, A3, A4, Cu_T, Duy_T, dt, Mm, Mmibf, Pp, Wcat, cubf);
  k_gm2  <<<64, 256, 0, stream>>>(By_T, Pp, Mm, Wcat, sq1);              // G, M^2
  k_m4cvt<<<64, 256, 0, stream>>>(sq1, Wcat, W0, W1, sq2, Wbf, W0bf, W1bf); // M^4 + converts
  k_mm   <<<64, 256, 0, stream>>>(sq2, sq2, sq1, 128);                   // M^8
  k_mm   <<<64, 256, 0, stream>>>(sq1, sq1, Mk, 128);                    // M^16

  // ---- big parallel work
  k_fused<<<NR/128, 256, 0, stream>>>(obs, Wbf, W0bf, W1bf, W2, b0, b1, b2, ls, cuy, out);
  k_phase1<<<C_CH*8, 256, 0, stream>>>(cuy, Mmibf, Dd);
  k_combine<<<B_, 256, 0, stream>>>(Mk, Dd, x0, XS, out + XFOFF);
  k_phase3<<<C_CH*8, 256, 0, stream>>>(cuy, Mmibf, cubf, XS, out);
}

// Round 13
// 276.035 us; speedup vs baseline: 1.1282x; 1.1282x over previous
//
#include <hip/hip_runtime.h>
#include <hip/hip_bf16.h>

#define B_    128
#define T_    2048
#define OBS_  128
#define S_    128
#define OUT_  64
#define H_    64
#define NR    (B_*T_)            // 262144 rows
#define K_CH  32                 // chunk length
#define C_CH  64                 // number of chunks
#define VOFF  (NR*2*OUT_)        // 33554432 : cur_value offset in d_out
#define XFOFF (VOFF + NR)        // 33816576 : x_final offset in d_out

typedef __attribute__((ext_vector_type(8))) short short8v;   // 8 bf16 (4 VGPRs)
typedef __attribute__((ext_vector_type(4))) float f32x4;

__device__ __forceinline__ unsigned short f2bf_hw(float f){
  __hip_bfloat16 h = __float2bfloat16(f);
  union { __hip_bfloat16 hh; unsigned short u; } cv; cv.hh = h; return cv.u;
}
__device__ __forceinline__ unsigned int pk2(float a, float b){
  __hip_bfloat162 h = __float22bfloat162_rn(make_float2(a, b));
  union { __hip_bfloat162 h2; unsigned int u; } cv; cv.h2 = h; return cv.u;
}
__device__ __forceinline__ float bf2f(unsigned short h){
  return __uint_as_float(((unsigned int)h) << 16);
}
__device__ __forceinline__ float fast_tanh(float x){
  float z = __builtin_exp2f(x * 2.88539008f);
  return 1.f - 2.f * __builtin_amdgcn_rcpf(z + 1.f);
}

// ---------------- generic 128x128 @ 128x128 matmul
__global__ __launch_bounds__(256) void k_mm(const float* __restrict__ A,
                                            const float* __restrict__ B,
                                            float* __restrict__ C, int ldc){
  int e = blockIdx.x * 256 + threadIdx.x;
  int r = e >> 7, c = e & 127;
  float acc = 0.f;
  #pragma unroll 4
  for (int k = 0; k < 128; ++k) acc += A[r*128 + k] * B[k*128 + c];
  C[r*ldc + c] = acc;
}

// ---------------- A3 = A2*A ; A4 = A2*A2
__global__ __launch_bounds__(256) void k_mm2(const float* __restrict__ A_T,
                                             const float* __restrict__ A2,
                                             float* __restrict__ A3,
                                             float* __restrict__ A4){
  int e = blockIdx.x * 256 + threadIdx.x;
  int r = e >> 7, c = e & 127;
  float a3 = 0.f, a4 = 0.f;
  #pragma unroll 4
  for (int k = 0; k < 128; ++k){
    float l = A2[r*128 + k];
    a3 += l * A_T[k*128 + c];
    a4 += l * A2[k*128 + c];
  }
  A3[e] = a3; A4[e] = a4;
}

// ---------------- build M, Mmi(bf16), P, Duy->Wcat, Cu->bf16
__global__ __launch_bounds__(256) void k_build(const float* __restrict__ A_T,
                                               const float* __restrict__ A2,
                                               const float* __restrict__ A3,
                                               const float* __restrict__ A4,
                                               const float* __restrict__ Cu_T,
                                               const float* __restrict__ Duy_T,
                                               const float* __restrict__ dtp,
                                               float* __restrict__ M,
                                               unsigned short* __restrict__ Mmibf,
                                               float* __restrict__ P, float* __restrict__ Wcat,
                                               unsigned short* __restrict__ cubf){
  float dt = *dtp;
  float d2 = dt*dt*0.5f;
  float d3 = d2*dt*(1.f/3.f);
  float d4 = d3*dt*0.25f;
  int e = blockIdx.x * 256 + threadIdx.x;
  int r = e >> 7, c = e & 127;
  float eye = (r == c) ? 1.f : 0.f;
  float mi = dt*A_T[e] + d2*A2[e] + d3*A3[e] + d4*A4[e];
  M[e] = eye + mi;
  Mmibf[e] = f2bf_hw(mi);
  P[e] = dt*eye + d2*A_T[e] + d3*A2[e] + d4*A3[e];
  if (e < 128*64){
    int k = e >> 6, o = e & 63;
    Wcat[k*192 + 128 + o] = Duy_T[e];
    cubf[e] = f2bf_hw(Cu_T[e]);
  }
}

// ---------------- Wcat-G = By*P ; sq1 = M^2
__global__ __launch_bounds__(256) void k_gm2(const float* __restrict__ By_T,
                                             const float* __restrict__ Pp,
                                             const float* __restrict__ Mm,
                                             float* __restrict__ Wcat,
                                             float* __restrict__ sq1){
  int e = blockIdx.x * 256 + threadIdx.x;
  int r = e >> 7, c = e & 127;
  float ga = 0.f, m2 = 0.f;
  #pragma unroll 4
  for (int k = 0; k < 128; ++k){
    ga += By_T[r*128 + k] * Pp[k*128 + c];
    m2 += Mm[r*128 + k] * Mm[k*128 + c];
  }
  Wcat[r*192 + c] = ga;
  sq1[e] = m2;
}

// ---------------- sq2 = M^4 ; convert Wbf/W0bf/W1bf
__global__ __launch_bounds__(256) void k_m4cvt(const float* __restrict__ sq1,
                                               const float* __restrict__ Wcat,
                                               const float* __restrict__ W0,
                                               const float* __restrict__ W1,
                                               float* __restrict__ sq2,
                                               unsigned short* __restrict__ Wbf,
                                               unsigned short* __restrict__ W0bf,
                                               unsigned short* __restrict__ W1bf){
  int e = blockIdx.x * 256 + threadIdx.x;
  int r = e >> 7, c = e & 127;
  float m4 = 0.f;
  #pragma unroll 4
  for (int k = 0; k < 128; ++k) m4 += sq1[r*128 + k] * sq1[k*128 + c];
  sq2[e] = m4;
  for (int i = e; i < 24576; i += 16384) Wbf[i] = f2bf_hw(Wcat[i]);
  if (e < 8192) W0bf[e] = f2bf_hw(W0[e]);
  if (e < 4096) W1bf[e] = f2bf_hw(W1[e]);
}

// ---------------- fused B1+B2 (MFMA), 128-row blocks, LDS-staged bf16 obs (R11 form)
__global__ __launch_bounds__(256) void k_fused(const float* __restrict__ obs,
                                               const unsigned short* __restrict__ Wbf,
                                               const unsigned short* __restrict__ W0bf,
                                               const unsigned short* __restrict__ W1bf,
                                               const float* __restrict__ W2,
                                               const float* __restrict__ b0g,
                                               const float* __restrict__ b1g,
                                               const float* __restrict__ b2g,
                                               const float* __restrict__ ls,
                                               unsigned short* __restrict__ cuy,
                                               float* __restrict__ out){
  __shared__ __align__(16) unsigned short ylds[64*136];
  __shared__ __align__(16) unsigned short ct[16*200];
  __shared__ __align__(16) unsigned short h0l[128*80];
  __shared__ float pl[128][4];
  int tid = threadIdx.x;
  int lane = tid & 63, w = tid >> 6;
  size_t row0 = (size_t)blockIdx.x * 128;
  int colbase = w * 48;
  int colh    = w * 16;
  int lr = lane & 15;
  int lk = (lane >> 4) * 8;

  short8v bfrag[3][4];
  #pragma unroll
  for (int cf = 0; cf < 3; ++cf)
    #pragma unroll
    for (int kk = 0; kk < 4; ++kk){
      short8v b;
      #pragma unroll
      for (int j = 0; j < 8; ++j)
        b[j] = (short)Wbf[(size_t)(kk*32 + lk + j)*192 + (colbase + cf*16 + lr)];
      bfrag[cf][kk] = b;
    }
  short8v bw0[4];
  #pragma unroll
  for (int kk = 0; kk < 4; ++kk)
    bw0[kk] = *(const short8v*)&W0bf[(size_t)(colh + lr)*128 + kk*32 + lk];
  short8v bw1[2];
  #pragma unroll
  for (int kk = 0; kk < 2; ++kk)
    bw1[kk] = *(const short8v*)&W1bf[(size_t)(colh + lr)*64 + kk*32 + lk];
  float b0v = b0g[colh + lr];
  float b1v = b1g[colh + lr];
  float w2v = W2[colh + lr];

  for (int h = 0; h < 2; ++h){
    { // cooperative staging: 8192 elems, 32/thread
      int base = tid * 32;
      int r = base >> 7, c0 = base & 127;
      const float* grow = obs + (row0 + h*64 + r) * 128;
      #pragma unroll
      for (int it = 0; it < 4; ++it){
        float4 a0 = *(const float4*)&grow[c0 + it*8];
        float4 a1 = *(const float4*)&grow[c0 + it*8 + 4];
        uint4 pv;
        pv.x = pk2(a0.x, a0.y); pv.y = pk2(a0.z, a0.w);
        pv.z = pk2(a1.x, a1.y); pv.w = pk2(a1.z, a1.w);
        *(uint4*)&ylds[r*136 + c0 + it*8] = pv;
      }
    }
    __syncthreads();
    for (int rfh = 0; rfh < 4; ++rfh){
      int rf = h*4 + rfh;
      f32x4 acc0 = {0.f,0.f,0.f,0.f}, acc1 = {0.f,0.f,0.f,0.f}, acc2 = {0.f,0.f,0.f,0.f};
      f32x4 acch = {0.f,0.f,0.f,0.f};
      #pragma unroll
      for (int kk = 0; kk < 4; ++kk){
        short8v af = *(const short8v*)&ylds[(rfh*16 + lr)*136 + kk*32 + lk];
        acc0 = __builtin_amdgcn_mfma_f32_16x16x32_bf16(af, bfrag[0][kk], acc0, 0, 0, 0);
        acc1 = __builtin_amdgcn_mfma_f32_16x16x32_bf16(af, bfrag[1][kk], acc1, 0, 0, 0);
        acc2 = __builtin_amdgcn_mfma_f32_16x16x32_bf16(af, bfrag[2][kk], acc2, 0, 0, 0);
        acch = __builtin_amdgcn_mfma_f32_16x16x32_bf16(af, bw0[kk],     acch, 0, 0, 0);
      }
      int orow = rf*16 + (lane >> 4)*4;
      int crow = (lane >> 4)*4;
      #pragma unroll
      for (int j = 0; j < 4; ++j){
        ct[(crow + j)*200 + colbase      + lr] = f2bf_hw(acc0[j]);
        ct[(crow + j)*200 + colbase + 16 + lr] = f2bf_hw(acc1[j]);
        ct[(crow + j)*200 + colbase + 32 + lr] = f2bf_hw(acc2[j]);
        h0l[(orow + j)*80 + colh + lr]         = f2bf_hw(fast_tanh(acch[j] + b0v));
      }
      __syncthreads();
      for (int li = tid; li < 16*24; li += 256){
        int r = li / 24, seg = li % 24;
        *(uint4*)&cuy[(row0 + h*64 + rfh*16 + r)*192 + seg*8] = *(const uint4*)&ct[r*200 + seg*8];
      }
      __syncthreads();
    }
  }

  for (int rf = 0; rf < 8; ++rf){
    f32x4 acc = {b1v, b1v, b1v, b1v};
    #pragma unroll
    for (int kk = 0; kk < 2; ++kk){
      short8v af = *(const short8v*)&h0l[(rf*16 + lr)*80 + kk*32 + lk];
      acc = __builtin_amdgcn_mfma_f32_16x16x32_bf16(af, bw1[kk], acc, 0, 0, 0);
    }
    float4 vpart;
    #pragma unroll
    for (int j = 0; j < 4; ++j) (&vpart.x)[j] = fast_tanh(acc[j]) * w2v;
    #pragma unroll
    for (int m = 1; m < 16; m <<= 1){
      vpart.x += __shfl_xor(vpart.x, m);
      vpart.y += __shfl_xor(vpart.y, m);
      vpart.z += __shfl_xor(vpart.z, m);
      vpart.w += __shfl_xor(vpart.w, m);
    }
    if (lr == 0){
      int orow = rf*16 + (lane >> 4)*4;
      #pragma unroll
      for (int j = 0; j < 4; ++j) pl[orow + j][w] = (&vpart.x)[j];
    }
  }
  __syncthreads();

  if (tid < 128)
    out[(size_t)VOFF + row0 + tid] = pl[tid][0] + pl[tid][1] + pl[tid][2] + pl[tid][3] + b2g[0];
  for (int li = tid; li < 128*16; li += 256){
    int r = li >> 4, c4 = li & 15;
    float4 lv = *(const float4*)&ls[c4*4];
    *(float4*)&out[(row0 + r)*128 + 64 + c4*4] = lv;
  }
}

// ---------------- phase 1 (MFMA), dual-chunk 16-row blocks: two independent chains/wave
__global__ __launch_bounds__(256) void k_phase1(const unsigned short* __restrict__ cuy,
                                                const unsigned short* __restrict__ Mmibf,
                                                float* __restrict__ Dd){
  __shared__ __align__(16) unsigned short xwA[16*136];
  __shared__ __align__(16) unsigned short xwB[16*136];
  int tid = threadIdx.x;
  int lane = tid & 63, w = tid >> 6;
  int lr = lane & 15, lg = lane >> 4;
  int pr = blockIdx.x >> 3, bi = blockIdx.x & 7;
  int b0 = bi*16;
  int ciA = 2*pr, ciB = 2*pr + 1;
  int t0A = ciA*K_CH, t0B = ciB*K_CH;
  int colbase = w*32;

  short8v bm[2][4];                            // M-I columns, shared by both chains
  #pragma unroll
  for (int ctt = 0; ctt < 2; ++ctt)
    #pragma unroll
    for (int kk = 0; kk < 4; ++kk){
      short8v b;
      #pragma unroll
      for (int j = 0; j < 8; ++j)
        b[j] = (short)Mmibf[(size_t)(kk*32 + lg*8 + j)*128 + colbase + ctt*16 + lr];
      bm[ctt][kk] = b;
    }

  f32x4 accA[2], accB[2];
  #pragma unroll
  for (int ctt = 0; ctt < 2; ++ctt)
    #pragma unroll
    for (int j = 0; j < 4; ++j){
      size_t rb = (size_t)(b0 + lg*4 + j)*T_;
      accA[ctt][j] = bf2f(cuy[(rb + t0A)*192 + colbase + ctt*16 + lr]);
      accB[ctt][j] = bf2f(cuy[(rb + t0B)*192 + colbase + ctt*16 + lr]);
    }

  for (int s = 1; s < K_CH; ++s){
    unsigned short cnA[2][4], cnB[2][4];
    #pragma unroll
    for (int ctt = 0; ctt < 2; ++ctt)
      #pragma unroll
      for (int j = 0; j < 4; ++j){
        size_t rb = (size_t)(b0 + lg*4 + j)*T_;
        cnA[ctt][j] = cuy[(rb + t0A + s)*192 + colbase + ctt*16 + lr];
        cnB[ctt][j] = cuy[(rb + t0B + s)*192 + colbase + ctt*16 + lr];
      }
    #pragma unroll
    for (int ctt = 0; ctt < 2; ++ctt)
      #pragma unroll
      for (int j = 0; j < 4; ++j){
        xwA[(lg*4 + j)*136 + colbase + ctt*16 + lr] = f2bf_hw(accA[ctt][j]);
        xwB[(lg*4 + j)*136 + colbase + ctt*16 + lr] = f2bf_hw(accB[ctt][j]);
      }
    __syncthreads();
    short8v afA[4], afB[4];
    #pragma unroll
    for (int kk = 0; kk < 4; ++kk){
      afA[kk] = *(const short8v*)&xwA[lr*136 + kk*32 + lg*8];
      afB[kk] = *(const short8v*)&xwB[lr*136 + kk*32 + lg*8];
    }
    __syncthreads();
    #pragma unroll
    for (int ctt = 0; ctt < 2; ++ctt)
      #pragma unroll
      for (int kk = 0; kk < 4; ++kk)
        accA[ctt] = __builtin_amdgcn_mfma_f32_16x16x32_bf16(afA[kk], bm[ctt][kk], accA[ctt], 0, 0, 0);
    #pragma unroll
    for (int ctt = 0; ctt < 2; ++ctt)
      #pragma unroll
      for (int kk = 0; kk < 4; ++kk)
        accB[ctt] = __builtin_amdgcn_mfma_f32_16x16x32_bf16(afB[kk], bm[ctt][kk], accB[ctt], 0, 0, 0);
    #pragma unroll
    for (int ctt = 0; ctt < 2; ++ctt)
      #pragma unroll
      for (int j = 0; j < 4; ++j){
        accA[ctt][j] += bf2f(cnA[ctt][j]);
        accB[ctt][j] += bf2f(cnB[ctt][j]);
      }
  }
  #pragma unroll
  for (int ctt = 0; ctt < 2; ++ctt)
    #pragma unroll
    for (int j = 0; j < 4; ++j){
      Dd[(size_t)ciA*16384 + (size_t)(b0 + lg*4 + j)*128 + colbase + ctt*16 + lr] = accA[ctt][j];
      Dd[(size_t)ciB*16384 + (size_t)(b0 + lg*4 + j)*128 + colbase + ctt*16 + lr] = accB[ctt][j];
    }
}

// ---------------- combine: sequential over 64 chunks, parallel over batch rows
__global__ __launch_bounds__(256) void k_combine(const float* __restrict__ Mk,
                                                 const float* __restrict__ Dd,
                                                 const float* __restrict__ x0,
                                                 float* __restrict__ XS,
                                                 float* __restrict__ xfin){
  __shared__ float xl[128];
  __shared__ float pl[256];
  int tid = threadIdx.x;
  int b = blockIdx.x;
  int c = tid & 127, h = tid >> 7;
  float mreg[64];
  #pragma unroll
  for (int j = 0; j < 64; ++j) mreg[j] = Mk[(64*h + j)*128 + c];
  if (tid < 128) xl[tid] = x0[(size_t)b*128 + tid];
  __syncthreads();
  for (int i = 0; i < C_CH; ++i){
    if (tid < 128) XS[(size_t)i*16384 + (size_t)b*128 + tid] = xl[tid];
    float part = 0.f;
    #pragma unroll
    for (int jj = 0; jj < 64; jj += 4){
      float4 xv = *(const float4*)&xl[64*h + jj];
      part += xv.x*mreg[jj] + xv.y*mreg[jj+1] + xv.z*mreg[jj+2] + xv.w*mreg[jj+3];
    }
    pl[tid] = part;
    __syncthreads();
    if (tid < 128)
      xl[tid] = pl[tid] + pl[tid + 128] + Dd[(size_t)i*16384 + (size_t)b*128 + tid];
    __syncthreads();
  }
  if (tid < 128) xfin[(size_t)b*128 + tid] = xl[tid];
}

// ---------------- phase 3 (MFMA), dual-chunk 16-row blocks: replay + fused u output
__global__ __launch_bounds__(256) void k_phase3(const unsigned short* __restrict__ cuy,
                                                const unsigned short* __restrict__ Mmibf,
                                                const unsigned short* __restrict__ cubf,
                                                const float* __restrict__ XS,
                                                float* __restrict__ out){
  __shared__ __align__(16) unsigned short xwA[16*136];
  __shared__ __align__(16) unsigned short xwB[16*136];
  int tid = threadIdx.x;
  int lane = tid & 63, w = tid >> 6;
  int lr = lane & 15, lg = lane >> 4;
  int pr = blockIdx.x >> 3, bi = blockIdx.x & 7;
  int b0 = bi*16;
  int ciA = 2*pr, ciB = 2*pr + 1;
  int t0A = ciA*K_CH, t0B = ciB*K_CH;
  int colbase = w*32;
  int ucolbase = w*16;

  short8v bm[2][4];
  #pragma unroll
  for (int ctt = 0; ctt < 2; ++ctt)
    #pragma unroll
    for (int kk = 0; kk < 4; ++kk){
      short8v b;
      #pragma unroll
      for (int j = 0; j < 8; ++j)
        b[j] = (short)Mmibf[(size_t)(kk*32 + lg*8 + j)*128 + colbase + ctt*16 + lr];
      bm[ctt][kk] = b;
    }
  short8v bc[4];
  #pragma unroll
  for (int kk = 0; kk < 4; ++kk){
    short8v b;
    #pragma unroll
    for (int j = 0; j < 8; ++j)
      b[j] = (short)cubf[(size_t)(kk*32 + lg*8 + j)*64 + ucolbase + lr];
    bc[kk] = b;
  }

  f32x4 accA[2], accB[2];
  #pragma unroll
  for (int ctt = 0; ctt < 2; ++ctt)
    #pragma unroll
    for (int j = 0; j < 4; ++j){
      size_t xb = (size_t)(b0 + lg*4 + j)*128 + colbase + ctt*16 + lr;
      accA[ctt][j] = XS[(size_t)ciA*16384 + xb];
      accB[ctt][j] = XS[(size_t)ciB*16384 + xb];
    }

  for (int s = 0; s < K_CH; ++s){
    f32x4 auA, auB;
    #pragma unroll
    for (int j = 0; j < 4; ++j){
      size_t rb = (size_t)(b0 + lg*4 + j)*T_;
      auA[j] = bf2f(cuy[(rb + t0A + s)*192 + 128 + ucolbase + lr]);
      auB[j] = bf2f(cuy[(rb + t0B + s)*192 + 128 + ucolbase + lr]);
    }
    unsigned short cnA[2][4], cnB[2][4];
    if (s + 1 < K_CH){
      #pragma unroll
      for (int ctt = 0; ctt < 2; ++ctt)
        #pragma unroll
        for (int j = 0; j < 4; ++j){
          size_t rb = (size_t)(b0 + lg*4 + j)*T_;
          cnA[ctt][j] = cuy[(rb + t0A + s)*192 + colbase + ctt*16 + lr];
          cnB[ctt][j] = cuy[(rb + t0B + s)*192 + colbase + ctt*16 + lr];
        }
    }
    #pragma unroll
    for (int ctt = 0; ctt < 2; ++ctt)
      #pragma unroll
      for (int j = 0; j < 4; ++j){
        xwA[(lg*4 + j)*136 + colbase + ctt*16 + lr] = f2bf_hw(accA[ctt][j]);
        xwB[(lg*4 + j)*136 + colbase + ctt*16 + lr] = f2bf_hw(accB[ctt][j]);
      }
    __syncthreads();
    short8v afA[4], afB[4];
    #pragma unroll
    for (int kk = 0; kk < 4; ++kk){
      afA[kk] = *(const short8v*)&xwA[lr*136 + kk*32 + lg*8];
      afB[kk] = *(const short8v*)&xwB[lr*136 + kk*32 + lg*8];
    }
    __syncthreads();
    // u outputs
    #pragma unroll
    for (int kk = 0; kk < 4; ++kk){
      auA = __builtin_amdgcn_mfma_f32_16x16x32_bf16(afA[kk], bc[kk], auA, 0, 0, 0);
      auB = __builtin_amdgcn_mfma_f32_16x16x32_bf16(afB[kk], bc[kk], auB, 0, 0, 0);
    }
    #pragma unroll
    for (int j = 0; j < 4; ++j){
      size_t rb = (size_t)(b0 + lg*4 + j)*T_;
      out[(rb + t0A + s)*128 + ucolbase + lr] = auA[j];
      out[(rb + t0B + s)*128 + ucolbase + lr] = auB[j];
    }
    // x updates (skip on last step)
    if (s + 1 < K_CH){
      #pragma unroll
      for (int ctt = 0; ctt < 2; ++ctt)
        #pragma unroll
        for (int kk = 0; kk < 4; ++kk)
          accA[ctt] = __builtin_amdgcn_mfma_f32_16x16x32_bf16(afA[kk], bm[ctt][kk], accA[ctt], 0, 0, 0);
      #pragma unroll
      for (int ctt = 0; ctt < 2; ++ctt)
        #pragma unroll
        for (int kk = 0; kk < 4; ++kk)
          accB[ctt] = __builtin_amdgcn_mfma_f32_16x16x32_bf16(afB[kk], bm[ctt][kk], accB[ctt], 0, 0, 0);
      #pragma unroll
      for (int ctt = 0; ctt < 2; ++ctt)
        #pragma unroll
        for (int j = 0; j < 4; ++j){
          accA[ctt][j] += bf2f(cnA[ctt][j]);
          accB[ctt][j] += bf2f(cnB[ctt][j]);
        }
    }
  }
}

extern "C" void kernel_launch(void* const* d_in, const int* in_sizes, int n_in,
                              void* d_out, int out_size, void* d_ws, size_t ws_size,
                              hipStream_t stream){
  const float* obs  = (const float*)d_in[0];
  const float* x0   = (const float*)d_in[1];
  const float* A_T  = (const float*)d_in[2];
  const float* By_T = (const float*)d_in[3];
  const float* Cu_T = (const float*)d_in[4];
  const float* Duy_T= (const float*)d_in[5];
  const float* ls   = (const float*)d_in[6];
  const float* W0   = (const float*)d_in[7];
  const float* b0   = (const float*)d_in[8];
  const float* W1   = (const float*)d_in[9];
  const float* b1   = (const float*)d_in[10];
  const float* W2   = (const float*)d_in[11];
  const float* b2   = (const float*)d_in[12];
  const float* dt   = (const float*)d_in[13];
  float* out = (float*)d_out;

  char* ws = (char*)d_ws;
  unsigned short* cuy = (unsigned short*)(ws + 0);            // 100663296 B
  float* A2     = (float*)(ws + 100663296);                   // 65536 each
  float* A3     = (float*)(ws + 100728832);
  float* A4     = (float*)(ws + 100794368);
  float* Mm     = (float*)(ws + 100859904);
  float* Pp     = (float*)(ws + 100925440);
  float* Mk     = (float*)(ws + 100990976);
  float* sq1    = (float*)(ws + 101056512);
  float* sq2    = (float*)(ws + 101122048);
  unsigned short* Mmibf = (unsigned short*)(ws + 101187584);  // 32768 B
  float* Wcat   = (float*)(ws + 101255168);                   // 98304 B
  unsigned short* cubf  = (unsigned short*)(ws + 101353472);  // 16384 B
  float* Dd     = (float*)(ws + 101387264);                   // 4194304 B
  float* XS     = (float*)(ws + 105581568);                   // 4194304 B
  unsigned short* Wbf  = (unsigned short*)Pp;                 // Pp dead after k_gm2 (49152 B)
  unsigned short* W0bf = (unsigned short*)A3;                 // A3 dead after k_build (16384 B)
  unsigned short* W1bf = (unsigned short*)A4;                 // A4 dead after k_build (8192 B)

  // ---- discrete setup chain (8 launches), Mk = M^32
  k_mm   <<<64, 256, 0, stream>>>(A_T, A_T, A2, 128);                    // A^2
  k_mm2  <<<64, 256, 0, stream>>>(A_T, A2, A3, A4);                      // A^3, A^4
  k_build<<<64, 256, 0, stream>>>(A_T, A2, A3, A4, Cu_T, Duy_T, dt, Mm, Mmibf, Pp, Wcat, cubf);
  k_gm2  <<<64, 256, 0, stream>>>(By_T, Pp, Mm, Wcat, sq1);              // G, M^2
  k_m4cvt<<<64, 256, 0, stream>>>(sq1, Wcat, W0, W1, sq2, Wbf, W0bf, W1bf); // M^4 + converts
  k_mm   <<<64, 256, 0, stream>>>(sq2, sq2, sq1, 128);                   // M^8
  k_mm   <<<64, 256, 0, stream>>>(sq1, sq1, sq2, 128);                   // M^16
  k_mm   <<<64, 256, 0, stream>>>(sq2, sq2, Mk, 128);                    // M^32

  // ---- big parallel work
  k_fused<<<NR/128, 256, 0, stream>>>(obs, Wbf, W0bf, W1bf, W2, b0, b1, b2, ls, cuy, out);
  k_phase1<<<(C_CH/2)*8, 256, 0, stream>>>(cuy, Mmibf, Dd);
  k_combine<<<B_, 256, 0, stream>>>(Mk, Dd, x0, XS, out + XFOFF);
  k_phase3<<<(C_CH/2)*8, 256, 0, stream>>>(cuy, Mmibf, cubf, XS, out);
}